// Round 1
// baseline (2478.297 us; speedup 1.0000x reference)
//
#include <hip/hip_runtime.h>
#include <hip/hip_bf16.h>

#define N_NODES 100000
#define N_EDGES 1600000
#define IN_C 512
#define HID_C 256
#define OUT_C 64
#define K_ITERS 10
#define ALPHA 0.1f

// ---------------------------------------------------------------------------
// CSR build kernels
// ---------------------------------------------------------------------------
__global__ void k_count(const int* __restrict__ ei, int* __restrict__ cnt, int E) {
    int e = blockIdx.x * blockDim.x + threadIdx.x;
    if (e < E) atomicAdd(&cnt[ei[E + e]], 1);
}

__global__ void k_dinv(const int* __restrict__ cnt, float* __restrict__ dinv, int n) {
    int i = blockIdx.x * blockDim.x + threadIdx.x;
    if (i < n) dinv[i] = rsqrtf((float)cnt[i] + 1.0f);  // +1 for self-loop
}

#define SCAN_T 1024
__global__ __launch_bounds__(SCAN_T) void k_scan(const int* __restrict__ cnt,
                                                 int* __restrict__ row_ptr,
                                                 int* __restrict__ cursor, int n) {
    __shared__ int sums[SCAN_T];
    int tid = threadIdx.x;
    int chunk = (n + SCAN_T - 1) / SCAN_T;
    int s = tid * chunk;
    int e = min(s + chunk, n);
    int local = 0;
    for (int i = s; i < e; ++i) local += cnt[i];
    sums[tid] = local;
    __syncthreads();
    for (int off = 1; off < SCAN_T; off <<= 1) {
        int v = (tid >= off) ? sums[tid - off] : 0;
        __syncthreads();
        sums[tid] += v;
        __syncthreads();
    }
    int run = sums[tid] - local;  // exclusive prefix
    for (int i = s; i < e; ++i) {
        row_ptr[i] = run;
        cursor[i] = run;
        run += cnt[i];
    }
    if (tid == SCAN_T - 1) row_ptr[n] = sums[SCAN_T - 1];
}

__global__ void k_fill(const int* __restrict__ ei, const float* __restrict__ dinv,
                       int* __restrict__ cursor, int* __restrict__ csr_src,
                       float* __restrict__ csr_w, int E) {
    int e = blockIdx.x * blockDim.x + threadIdx.x;
    if (e < E) {
        int s = ei[e];
        int d = ei[E + e];
        int pos = atomicAdd(&cursor[d], 1);
        csr_src[pos] = s;
        csr_w[pos] = dinv[s] * dinv[d];
    }
}

// ---------------------------------------------------------------------------
// Fused MLP: h = relu(x @ W1^T + b1) @ W2^T + b2, written to h0 and hcur
// 64 rows per block, 256 threads. Phase 1: 64x256 H1 tile (acc in regs,
// LDS-staged X/W1 tiles). Phase 2: H1 (LDS) @ W2^T -> 64x64 out tile.
// ---------------------------------------------------------------------------
__global__ __launch_bounds__(256) void k_mlp(const float* __restrict__ x,
                                             const float* __restrict__ w1,
                                             const float* __restrict__ b1,
                                             const float* __restrict__ w2,
                                             const float* __restrict__ b2,
                                             float* __restrict__ h0,
                                             float* __restrict__ hcur, int n) {
    __shared__ union {
        struct { float Xs[64][36]; float W1s[256][36]; } p1;
        struct { float H1s[64][260]; } p2;
    } sm;
    const int tid = threadIdx.x;
    const int row0 = blockIdx.x * 64;
    const int tx = tid & 15;   // col group (16 cols, stride 16)
    const int ty = tid >> 4;   // row group (4 rows, stride 16)

    float acc[4][16];
#pragma unroll
    for (int i = 0; i < 4; ++i)
#pragma unroll
        for (int j = 0; j < 16; ++j) acc[i][j] = 0.0f;

    for (int k0 = 0; k0 < IN_C; k0 += 32) {
        // stage X tile: 64x32 floats = 512 float4, 2 per thread
#pragma unroll
        for (int j = 0; j < 2; ++j) {
            int f4 = tid + 256 * j;
            int r = f4 >> 3, kk = (f4 & 7) * 4;
            int gr = row0 + r;
            if (gr >= n) gr = n - 1;
            *(float4*)&sm.p1.Xs[r][kk] = *(const float4*)&x[(size_t)gr * IN_C + k0 + kk];
        }
        // stage W1 tile: 256x32 floats = 2048 float4, 8 per thread
#pragma unroll
        for (int j = 0; j < 8; ++j) {
            int f4 = tid + 256 * j;
            int c = f4 >> 3, kk = (f4 & 7) * 4;
            *(float4*)&sm.p1.W1s[c][kk] = *(const float4*)&w1[(size_t)c * IN_C + k0 + kk];
        }
        __syncthreads();
#pragma unroll
        for (int kk = 0; kk < 32; kk += 2) {
            float2 xv[4], wv[16];
#pragma unroll
            for (int i = 0; i < 4; ++i) xv[i] = *(const float2*)&sm.p1.Xs[ty + 16 * i][kk];
#pragma unroll
            for (int j = 0; j < 16; ++j) wv[j] = *(const float2*)&sm.p1.W1s[tx + 16 * j][kk];
#pragma unroll
            for (int i = 0; i < 4; ++i)
#pragma unroll
                for (int j = 0; j < 16; ++j) {
                    acc[i][j] += xv[i].x * wv[j].x;
                    acc[i][j] += xv[i].y * wv[j].y;
                }
        }
        __syncthreads();
    }

    // bias + relu -> H1 LDS tile (union switch: all p1 reads synced above)
#pragma unroll
    for (int j = 0; j < 16; ++j) {
        int c = tx + 16 * j;
        float bb = b1[c];
#pragma unroll
        for (int i = 0; i < 4; ++i) {
            float h = acc[i][j] + bb;
            sm.p2.H1s[ty + 16 * i][c] = h > 0.0f ? h : 0.0f;
        }
    }
    __syncthreads();

    // Phase 2: out[64][64] = H1 @ W2^T + b2
    const int rg = tid >> 4;  // 16 row groups x 4 rows
    const int og = tid & 15;  // 16 out groups x 4 outs
    float acc2[4][4];
#pragma unroll
    for (int i = 0; i < 4; ++i)
#pragma unroll
        for (int j = 0; j < 4; ++j) acc2[i][j] = 0.0f;

    for (int k = 0; k < HID_C; k += 4) {
        float4 h4[4], w4[4];
#pragma unroll
        for (int i = 0; i < 4; ++i) h4[i] = *(const float4*)&sm.p2.H1s[rg * 4 + i][k];
#pragma unroll
        for (int j = 0; j < 4; ++j) w4[j] = *(const float4*)&w2[(size_t)(og * 4 + j) * HID_C + k];
#pragma unroll
        for (int i = 0; i < 4; ++i)
#pragma unroll
            for (int j = 0; j < 4; ++j) {
                acc2[i][j] += h4[i].x * w4[j].x;
                acc2[i][j] += h4[i].y * w4[j].y;
                acc2[i][j] += h4[i].z * w4[j].z;
                acc2[i][j] += h4[i].w * w4[j].w;
            }
    }

#pragma unroll
    for (int i = 0; i < 4; ++i) {
        int gr = row0 + rg * 4 + i;
        if (gr < n) {
            float4 o;
            o.x = acc2[i][0] + b2[og * 4 + 0];
            o.y = acc2[i][1] + b2[og * 4 + 1];
            o.z = acc2[i][2] + b2[og * 4 + 2];
            o.w = acc2[i][3] + b2[og * 4 + 3];
            *(float4*)&h0[(size_t)gr * OUT_C + og * 4] = o;
            *(float4*)&hcur[(size_t)gr * OUT_C + og * 4] = o;
        }
    }
}

// ---------------------------------------------------------------------------
// Propagation: hout[i] = 0.9*(sum_e w_e*hin[src_e] + dinv[i]^2*hin[i]) + 0.1*h0[i]
// One wave (64 lanes = 64 channels) per node, 4 nodes per block.
// ---------------------------------------------------------------------------
__global__ __launch_bounds__(256) void k_prop(const float* __restrict__ hin,
                                              const float* __restrict__ h0,
                                              float* __restrict__ hout,
                                              const int* __restrict__ row_ptr,
                                              const int* __restrict__ csr_src,
                                              const float* __restrict__ csr_w,
                                              const float* __restrict__ dinv, int n) {
    int node = blockIdx.x * 4 + threadIdx.y;
    if (node >= n) return;
    int c = threadIdx.x;
    float dv = dinv[node];
    float acc = dv * dv * hin[(size_t)node * OUT_C + c];
    int e0 = row_ptr[node], e1 = row_ptr[node + 1];
    int e = e0;
    for (; e + 1 < e1; e += 2) {
        int s0 = csr_src[e], s1 = csr_src[e + 1];
        float w0 = csr_w[e], w1v = csr_w[e + 1];
        acc += w0 * hin[(size_t)s0 * OUT_C + c];
        acc += w1v * hin[(size_t)s1 * OUT_C + c];
    }
    if (e < e1) acc += csr_w[e] * hin[(size_t)csr_src[e] * OUT_C + c];
    hout[(size_t)node * OUT_C + c] = (1.0f - ALPHA) * acc + ALPHA * h0[(size_t)node * OUT_C + c];
}

// ---------------------------------------------------------------------------
extern "C" void kernel_launch(void* const* d_in, const int* in_sizes, int n_in,
                              void* d_out, int out_size, void* d_ws, size_t ws_size,
                              hipStream_t stream) {
    const float* x  = (const float*)d_in[0];
    const int*   ei = (const int*)d_in[1];
    const float* w1 = (const float*)d_in[2];
    const float* b1 = (const float*)d_in[3];
    const float* w2 = (const float*)d_in[4];
    const float* b2 = (const float*)d_in[5];
    float* dout = (float*)d_out;

    const int N = N_NODES;
    const int E = N_EDGES;

    // workspace layout
    float* hB      = (float*)d_ws;                 // N*64
    float* h0      = hB + (size_t)N * OUT_C;       // N*64
    float* dinv    = h0 + (size_t)N * OUT_C;       // N
    int*   cnt     = (int*)(dinv + N);             // N
    int*   row_ptr = cnt + N;                      // N+1
    int*   cursor  = row_ptr + (N + 1);            // N
    int*   csr_src = cursor + N;                   // E
    float* csr_w   = (float*)(csr_src + E);        // E

    hipMemsetAsync(cnt, 0, (size_t)N * sizeof(int), stream);

    k_count<<<(E + 255) / 256, 256, 0, stream>>>(ei, cnt, E);
    k_dinv<<<(N + 255) / 256, 256, 0, stream>>>(cnt, dinv, N);
    k_scan<<<1, SCAN_T, 0, stream>>>(cnt, row_ptr, cursor, N);
    k_fill<<<(E + 255) / 256, 256, 0, stream>>>(ei, dinv, cursor, csr_src, csr_w, E);

    k_mlp<<<(N + 63) / 64, 256, 0, stream>>>(x, w1, b1, w2, b2, h0, dout, N);

    for (int it = 0; it < K_ITERS; ++it) {
        const float* pin = (it & 1) ? hB : dout;
        float* pout = (it & 1) ? dout : hB;
        dim3 blk(64, 4);
        k_prop<<<(N + 3) / 4, blk, 0, stream>>>(pin, h0, pout, row_ptr, csr_src, csr_w, dinv, N);
    }
}

// Round 2
// 1551.167 us; speedup vs baseline: 1.5977x; 1.5977x over previous
//
#include <hip/hip_runtime.h>
#include <hip/hip_bf16.h>

#define N_NODES 100000
#define N_EDGES 1600000
#define IN_C 512
#define HID_C 256
#define OUT_C 64
#define K_ITERS 10
#define ALPHA 0.1f

typedef __bf16 bf16x8 __attribute__((ext_vector_type(8)));
typedef __bf16 bf16x4 __attribute__((ext_vector_type(4)));
typedef float f32x4 __attribute__((ext_vector_type(4)));

#define MFMA(a, b, c) __builtin_amdgcn_mfma_f32_16x16x32_bf16((a), (b), (c), 0, 0, 0)

__device__ __forceinline__ void gload16(const void* g, void* l) {
    __builtin_amdgcn_global_load_lds(
        (const __attribute__((address_space(1))) unsigned int*)g,
        (__attribute__((address_space(3))) unsigned int*)l, 16, 0, 0);
}

// ---------------------------------------------------------------------------
// CSR build kernels
// ---------------------------------------------------------------------------
__global__ void k_count(const int* __restrict__ ei, int* __restrict__ cnt, int E) {
    int e = blockIdx.x * blockDim.x + threadIdx.x;
    if (e < E) atomicAdd(&cnt[ei[E + e]], 1);
}

__global__ void k_dinv(const int* __restrict__ cnt, float* __restrict__ dinv, int n) {
    int i = blockIdx.x * blockDim.x + threadIdx.x;
    if (i < n) dinv[i] = rsqrtf((float)cnt[i] + 1.0f);  // +1 for self-loop
}

#define SCAN_T 1024
__global__ __launch_bounds__(SCAN_T) void k_scan(const int* __restrict__ cnt,
                                                 int* __restrict__ row_ptr,
                                                 int* __restrict__ cursor, int n) {
    __shared__ int sums[SCAN_T];
    int tid = threadIdx.x;
    int chunk = (n + SCAN_T - 1) / SCAN_T;
    int s = tid * chunk;
    int e = min(s + chunk, n);
    int local = 0;
    for (int i = s; i < e; ++i) local += cnt[i];
    sums[tid] = local;
    __syncthreads();
    for (int off = 1; off < SCAN_T; off <<= 1) {
        int v = (tid >= off) ? sums[tid - off] : 0;
        __syncthreads();
        sums[tid] += v;
        __syncthreads();
    }
    int run = sums[tid] - local;  // exclusive prefix
    for (int i = s; i < e; ++i) {
        row_ptr[i] = run;
        cursor[i] = run;
        run += cnt[i];
    }
    if (tid == SCAN_T - 1) row_ptr[n] = sums[SCAN_T - 1];
}

__global__ void k_fill(const int* __restrict__ ei, const float* __restrict__ dinv,
                       int* __restrict__ cursor, int* __restrict__ csr_src,
                       float* __restrict__ csr_w, int E) {
    int e = blockIdx.x * blockDim.x + threadIdx.x;
    if (e < E) {
        int s = ei[e];
        int d = ei[E + e];
        int pos = atomicAdd(&cursor[d], 1);
        csr_src[pos] = s;
        csr_w[pos] = dinv[s] * dinv[d];
    }
}

// ---------------------------------------------------------------------------
// Weight split: f32 -> (hi bf16, lo bf16), hi+lo ~ f32 to ~2^-16 rel.
// ---------------------------------------------------------------------------
__global__ void k_split(const float* __restrict__ in, __bf16* __restrict__ hi,
                        __bf16* __restrict__ lo, int n) {
    int i = blockIdx.x * blockDim.x + threadIdx.x;
    if (i < n) {
        float f = in[i];
        __bf16 h = (__bf16)f;
        hi[i] = h;
        lo[i] = (__bf16)(f - (float)h);
    }
}

// ---------------------------------------------------------------------------
// Fused split-bf16 MFMA MLP: out = relu(x@W1^T+b1)@W2^T+b2 -> h0, hcur.
// Block = 256 threads (4 waves), tile M=64 x N=256, BK=32.
// Wave w computes output cols [w*64, w*64+64) as 4x4 frags of 16x16x32 MFMA.
// Split precision: acc += Ah*Bh + Ah*Bl + Al*Bh  (Al*Bl negligible).
// A: reg-staged f32->hi/lo into padded LDS [64][40] (2-way conflicts = free).
// B: global_load_lds from pre-split w1 hi/lo, source-side chunk swizzle
//    kc ^= (row>>1)&3 to break the 64B-row-stride bank conflict.
// Phase 2 (K=256) reads hi/lo H1 from LDS (row pad 264) + w2 frags from L2.
// ---------------------------------------------------------------------------
__global__ __launch_bounds__(256, 2) void k_mlp2(
    const float* __restrict__ x,
    const __bf16* __restrict__ w1h, const __bf16* __restrict__ w1l,
    const float* __restrict__ b1,
    const __bf16* __restrict__ w2h, const __bf16* __restrict__ w2l,
    const float* __restrict__ b2,
    float* __restrict__ h0, float* __restrict__ hcur, int n) {
    __shared__ __align__(16) union {
        struct {
            __bf16 Ah[64 * 40];   // 5120 B, rows padded to 40 bf16 (80 B)
            __bf16 Al[64 * 40];   // 5120 B
            __bf16 Bh[256 * 32];  // 16384 B, chunk-swizzled
            __bf16 Bl[256 * 32];  // 16384 B
        } p1;
        struct {
            __bf16 Hh[64 * 264];  // 33792 B, rows padded to 264 bf16
            __bf16 Hl[64 * 264];  // 33792 B
        } p2;
    } sm;

    const int tid = threadIdx.x;
    const int l = tid & 63;
    const int w = tid >> 6;   // wave id 0..3
    const int lr = l & 15;    // A-row / B-col within frag
    const int kg = l >> 4;    // k-chunk group 0..3 (8 bf16 each)
    const int row0 = blockIdx.x * 64;

    f32x4 acc[4][4];
#pragma unroll
    for (int m = 0; m < 4; ++m)
#pragma unroll
        for (int nf = 0; nf < 4; ++nf) acc[m][nf] = (f32x4)0.0f;

    for (int k0 = 0; k0 < IN_C; k0 += 32) {
        // ---- stage B (w1 hi/lo tile rows 0..255, cols k0..k0+31) ----
        // LDS slot s holds 16B chunk (row = s>>2, kc = (s&3) ^ ((row>>1)&3)).
#pragma unroll
        for (int i = 0; i < 4; ++i) {
            int slot = tid + 256 * i;
            int row = slot >> 2;
            int kc = (slot & 3) ^ ((row >> 1) & 3);
            size_t goff = (size_t)row * IN_C + k0 + kc * 8;
            int sbase = (w * 64 + 256 * i) * 8;  // wave-uniform, lane adds 16B
            gload16(w1h + goff, &sm.p1.Bh[sbase]);
            gload16(w1l + goff, &sm.p1.Bl[sbase]);
        }
        // ---- stage A (x rows row0..row0+63, cols k0..k0+31) with cvt ----
#pragma unroll
        for (int i = 0; i < 2; ++i) {
            int f4 = tid + 256 * i;
            int r = f4 >> 3;
            int kk = (f4 & 7) * 4;
            int gr = row0 + r;
            if (gr >= n) gr = n - 1;
            float4 v = *(const float4*)&x[(size_t)gr * IN_C + k0 + kk];
            float vv[4] = {v.x, v.y, v.z, v.w};
            bf16x4 h4, l4;
#pragma unroll
            for (int j = 0; j < 4; ++j) {
                __bf16 hb = (__bf16)vv[j];
                h4[j] = hb;
                l4[j] = (__bf16)(vv[j] - (float)hb);
            }
            *(bf16x4*)&sm.p1.Ah[r * 40 + kk] = h4;
            *(bf16x4*)&sm.p1.Al[r * 40 + kk] = l4;
        }
        __syncthreads();  // staging (incl. global_load_lds) visible

        bf16x8 ah[4], al[4], bh[4], bl[4];
#pragma unroll
        for (int m = 0; m < 4; ++m) {
            int ao = (m * 16 + lr) * 40 + kg * 8;
            ah[m] = *(const bf16x8*)&sm.p1.Ah[ao];
            al[m] = *(const bf16x8*)&sm.p1.Al[ao];
        }
#pragma unroll
        for (int nf = 0; nf < 4; ++nf) {
            int row = w * 64 + nf * 16 + lr;
            int kc = kg ^ ((row >> 1) & 3);
            int bo = row * 32 + kc * 8;
            bh[nf] = *(const bf16x8*)&sm.p1.Bh[bo];
            bl[nf] = *(const bf16x8*)&sm.p1.Bl[bo];
        }
#pragma unroll
        for (int m = 0; m < 4; ++m)
#pragma unroll
            for (int nf = 0; nf < 4; ++nf) {
                acc[m][nf] = MFMA(ah[m], bh[nf], acc[m][nf]);
                acc[m][nf] = MFMA(ah[m], bl[nf], acc[m][nf]);
                acc[m][nf] = MFMA(al[m], bh[nf], acc[m][nf]);
            }
        __syncthreads();  // compute done before next-step staging overwrite
    }

    // ---- epilogue 1: bias + relu, split to hi/lo H1 in LDS ----
#pragma unroll
    for (int m = 0; m < 4; ++m)
#pragma unroll
        for (int nf = 0; nf < 4; ++nf) {
            int col = w * 64 + nf * 16 + lr;
            float bb = b1[col];
#pragma unroll
            for (int r = 0; r < 4; ++r) {
                int row = m * 16 + kg * 4 + r;  // C/D: row=(lane>>4)*4+reg
                float hv = acc[m][nf][r] + bb;
                hv = fmaxf(hv, 0.0f);
                __bf16 hb = (__bf16)hv;
                sm.p2.Hh[row * 264 + col] = hb;
                sm.p2.Hl[row * 264 + col] = (__bf16)(hv - (float)hb);
            }
        }
    __syncthreads();

    // ---- phase 2: out[64][64] = H1 @ W2^T + b2, wave w does cols w*16.. ----
    f32x4 acc2[4];
#pragma unroll
    for (int m = 0; m < 4; ++m) acc2[m] = (f32x4)0.0f;
    const int col2 = w * 16 + lr;

#pragma unroll
    for (int k0 = 0; k0 < HID_C; k0 += 32) {
        size_t wo = (size_t)col2 * HID_C + k0 + kg * 8;
        bf16x8 b2h = *(const bf16x8*)&w2h[wo];
        bf16x8 b2l = *(const bf16x8*)&w2l[wo];
#pragma unroll
        for (int m = 0; m < 4; ++m) {
            int ho = (m * 16 + lr) * 264 + k0 + kg * 8;
            bf16x8 a2h = *(const bf16x8*)&sm.p2.Hh[ho];
            bf16x8 a2l = *(const bf16x8*)&sm.p2.Hl[ho];
            acc2[m] = MFMA(a2h, b2h, acc2[m]);
            acc2[m] = MFMA(a2h, b2l, acc2[m]);
            acc2[m] = MFMA(a2l, b2h, acc2[m]);
        }
    }

    float bb2 = b2[col2];
#pragma unroll
    for (int m = 0; m < 4; ++m)
#pragma unroll
        for (int r = 0; r < 4; ++r) {
            int grow = row0 + m * 16 + kg * 4 + r;
            if (grow < n) {
                float vv = acc2[m][r] + bb2;
                h0[(size_t)grow * OUT_C + col2] = vv;
                hcur[(size_t)grow * OUT_C + col2] = vv;
            }
        }
}

// ---------------------------------------------------------------------------
// Propagation: hout[i] = 0.9*(sum_e w_e*hin[src_e] + dinv[i]^2*hin[i]) + 0.1*h0[i]
// One wave (64 lanes = 64 channels) per node, 4 nodes per block.
// ---------------------------------------------------------------------------
__global__ __launch_bounds__(256) void k_prop(const float* __restrict__ hin,
                                              const float* __restrict__ h0,
                                              float* __restrict__ hout,
                                              const int* __restrict__ row_ptr,
                                              const int* __restrict__ csr_src,
                                              const float* __restrict__ csr_w,
                                              const float* __restrict__ dinv, int n) {
    int node = blockIdx.x * 4 + threadIdx.y;
    if (node >= n) return;
    int c = threadIdx.x;
    float dv = dinv[node];
    float acc = dv * dv * hin[(size_t)node * OUT_C + c];
    int e0 = row_ptr[node], e1 = row_ptr[node + 1];
    int e = e0;
    for (; e + 1 < e1; e += 2) {
        int s0 = csr_src[e], s1 = csr_src[e + 1];
        float w0 = csr_w[e], w1v = csr_w[e + 1];
        acc += w0 * hin[(size_t)s0 * OUT_C + c];
        acc += w1v * hin[(size_t)s1 * OUT_C + c];
    }
    if (e < e1) acc += csr_w[e] * hin[(size_t)csr_src[e] * OUT_C + c];
    hout[(size_t)node * OUT_C + c] = (1.0f - ALPHA) * acc + ALPHA * h0[(size_t)node * OUT_C + c];
}

// ---------------------------------------------------------------------------
extern "C" void kernel_launch(void* const* d_in, const int* in_sizes, int n_in,
                              void* d_out, int out_size, void* d_ws, size_t ws_size,
                              hipStream_t stream) {
    const float* x  = (const float*)d_in[0];
    const int*   ei = (const int*)d_in[1];
    const float* w1 = (const float*)d_in[2];
    const float* b1 = (const float*)d_in[3];
    const float* w2 = (const float*)d_in[4];
    const float* b2 = (const float*)d_in[5];
    float* dout = (float*)d_out;

    const int N = N_NODES;
    const int E = N_EDGES;

    // workspace layout
    float* hB      = (float*)d_ws;                 // N*64
    float* h0      = hB + (size_t)N * OUT_C;       // N*64
    float* dinv    = h0 + (size_t)N * OUT_C;       // N
    int*   cnt     = (int*)(dinv + N);             // N
    int*   row_ptr = cnt + N;                      // N+1
    int*   cursor  = row_ptr + (N + 1);            // N
    int*   csr_src = cursor + N;                   // E
    float* csr_w   = (float*)(csr_src + E);        // E
    __bf16* w1h    = (__bf16*)(csr_w + E);         // 256*512
    __bf16* w1l    = w1h + (size_t)HID_C * IN_C;   // 256*512
    __bf16* w2h    = w1l + (size_t)HID_C * IN_C;   // 64*256
    __bf16* w2l    = w2h + (size_t)OUT_C * HID_C;  // 64*256

    hipMemsetAsync(cnt, 0, (size_t)N * sizeof(int), stream);

    k_count<<<(E + 255) / 256, 256, 0, stream>>>(ei, cnt, E);
    k_dinv<<<(N + 255) / 256, 256, 0, stream>>>(cnt, dinv, N);
    k_scan<<<1, SCAN_T, 0, stream>>>(cnt, row_ptr, cursor, N);
    k_fill<<<(E + 255) / 256, 256, 0, stream>>>(ei, dinv, cursor, csr_src, csr_w, E);

    k_split<<<(HID_C * IN_C + 255) / 256, 256, 0, stream>>>(w1, w1h, w1l, HID_C * IN_C);
    k_split<<<(OUT_C * HID_C + 255) / 256, 256, 0, stream>>>(w2, w2h, w2l, OUT_C * HID_C);

    k_mlp2<<<(N + 63) / 64, 256, 0, stream>>>(x, w1h, w1l, b1, w2h, w2l, b2, h0, dout, N);

    for (int it = 0; it < K_ITERS; ++it) {
        const float* pin = (it & 1) ? hB : dout;
        float* pout = (it & 1) ? dout : hB;
        dim3 blk(64, 4);
        k_prop<<<(N + 3) / 4, blk, 0, stream>>>(pin, h0, pout, row_ptr, csr_src, csr_w, dinv, N);
    }
}

// Round 3
// 1108.107 us; speedup vs baseline: 2.2365x; 1.3998x over previous
//
#include <hip/hip_runtime.h>
#include <hip/hip_bf16.h>

#define N_NODES 100000
#define N_EDGES 1600000
#define IN_C 512
#define HID_C 256
#define OUT_C 64
#define K_ITERS 10
#define ALPHA 0.1f

typedef __bf16 bf16x8 __attribute__((ext_vector_type(8)));
typedef __bf16 bf16x4 __attribute__((ext_vector_type(4)));
typedef float f32x4 __attribute__((ext_vector_type(4)));

#define MFMA(a, b, c) __builtin_amdgcn_mfma_f32_16x16x32_bf16((a), (b), (c), 0, 0, 0)

__device__ __forceinline__ void gload16(const void* g, void* l) {
    __builtin_amdgcn_global_load_lds(
        (const __attribute__((address_space(1))) unsigned int*)g,
        (__attribute__((address_space(3))) unsigned int*)l, 16, 0, 0);
}

// ---------------------------------------------------------------------------
// CSR build kernels
// ---------------------------------------------------------------------------
__global__ void k_count(const int* __restrict__ ei, int* __restrict__ cnt, int E) {
    int e = blockIdx.x * blockDim.x + threadIdx.x;
    if (e < E) atomicAdd(&cnt[ei[E + e]], 1);
}

__global__ void k_dinv(const int* __restrict__ cnt, float* __restrict__ dinv, int n) {
    int i = blockIdx.x * blockDim.x + threadIdx.x;
    if (i < n) dinv[i] = rsqrtf((float)cnt[i] + 1.0f);  // +1 for self-loop
}

// ---------------------------------------------------------------------------
// Two-level scan: 1024 elems/block (256 thr x 4).
// ---------------------------------------------------------------------------
#define SCB 1024
__global__ __launch_bounds__(256) void k_scan1(const int* __restrict__ cnt,
                                               int* __restrict__ bsum, int n) {
    __shared__ int s[256];
    int b = blockIdx.x, t = threadIdx.x;
    int base = b * SCB + t * 4;
    int local = 0;
#pragma unroll
    for (int j = 0; j < 4; ++j) {
        int i = base + j;
        if (i < n) local += cnt[i];
    }
    s[t] = local;
    __syncthreads();
    for (int off = 1; off < 256; off <<= 1) {
        int u = (t >= off) ? s[t - off] : 0;
        __syncthreads();
        s[t] += u;
        __syncthreads();
    }
    if (t == 255) bsum[b] = s[255];
}

__global__ __launch_bounds__(128) void k_scan2(const int* __restrict__ bsum,
                                               int* __restrict__ boff, int G,
                                               int* __restrict__ row_ptr, int n, int total) {
    __shared__ int s[128];
    int t = threadIdx.x;
    int v = (t < G) ? bsum[t] : 0;
    s[t] = v;
    __syncthreads();
    for (int off = 1; off < 128; off <<= 1) {
        int u = (t >= off) ? s[t - off] : 0;
        __syncthreads();
        s[t] += u;
        __syncthreads();
    }
    if (t < G) boff[t] = s[t] - v;
    if (t == 0) row_ptr[n] = total;
}

__global__ __launch_bounds__(256) void k_scan3(const int* __restrict__ cnt,
                                               const int* __restrict__ boff,
                                               int* __restrict__ row_ptr,
                                               int* __restrict__ cursor, int n) {
    __shared__ int s[256];
    int b = blockIdx.x, t = threadIdx.x;
    int base = b * SCB + t * 4;
    int c4[4];
    int local = 0;
#pragma unroll
    for (int j = 0; j < 4; ++j) {
        int i = base + j;
        c4[j] = (i < n) ? cnt[i] : 0;
        local += c4[j];
    }
    s[t] = local;
    __syncthreads();
    for (int off = 1; off < 256; off <<= 1) {
        int u = (t >= off) ? s[t - off] : 0;
        __syncthreads();
        s[t] += u;
        __syncthreads();
    }
    int run = boff[b] + s[t] - local;
#pragma unroll
    for (int j = 0; j < 4; ++j) {
        int i = base + j;
        if (i < n) {
            row_ptr[i] = run;
            cursor[i] = run;
            run += c4[j];
        }
    }
}

__global__ void k_fill(const int* __restrict__ ei, const float* __restrict__ dinv,
                       int* __restrict__ cursor, int* __restrict__ csr_src,
                       float* __restrict__ csr_w, int E) {
    int e = blockIdx.x * blockDim.x + threadIdx.x;
    if (e < E) {
        int s = ei[e];
        int d = ei[E + e];
        int pos = atomicAdd(&cursor[d], 1);
        csr_src[pos] = s;
        csr_w[pos] = dinv[s] * dinv[d];
    }
}

// ---------------------------------------------------------------------------
// Weight split: f32 -> (hi bf16, lo bf16), hi+lo ~ f32 to ~2^-16 rel.
// ---------------------------------------------------------------------------
__global__ void k_split(const float* __restrict__ in, __bf16* __restrict__ hi,
                        __bf16* __restrict__ lo, int n) {
    int i = blockIdx.x * blockDim.x + threadIdx.x;
    if (i < n) {
        float f = in[i];
        __bf16 h = (__bf16)f;
        hi[i] = h;
        lo[i] = (__bf16)(f - (float)h);
    }
}

// ---------------------------------------------------------------------------
// Fused split-bf16 MFMA MLP (unchanged from round 1; see comments there).
// ---------------------------------------------------------------------------
__global__ __launch_bounds__(256, 2) void k_mlp2(
    const float* __restrict__ x,
    const __bf16* __restrict__ w1h, const __bf16* __restrict__ w1l,
    const float* __restrict__ b1,
    const __bf16* __restrict__ w2h, const __bf16* __restrict__ w2l,
    const float* __restrict__ b2,
    float* __restrict__ h0, float* __restrict__ hcur, int n) {
    __shared__ __align__(16) union {
        struct {
            __bf16 Ah[64 * 40];
            __bf16 Al[64 * 40];
            __bf16 Bh[256 * 32];
            __bf16 Bl[256 * 32];
        } p1;
        struct {
            __bf16 Hh[64 * 264];
            __bf16 Hl[64 * 264];
        } p2;
    } sm;

    const int tid = threadIdx.x;
    const int l = tid & 63;
    const int w = tid >> 6;
    const int lr = l & 15;
    const int kg = l >> 4;
    const int row0 = blockIdx.x * 64;

    f32x4 acc[4][4];
#pragma unroll
    for (int m = 0; m < 4; ++m)
#pragma unroll
        for (int nf = 0; nf < 4; ++nf) acc[m][nf] = (f32x4)0.0f;

    for (int k0 = 0; k0 < IN_C; k0 += 32) {
#pragma unroll
        for (int i = 0; i < 4; ++i) {
            int slot = tid + 256 * i;
            int row = slot >> 2;
            int kc = (slot & 3) ^ ((row >> 1) & 3);
            size_t goff = (size_t)row * IN_C + k0 + kc * 8;
            int sbase = (w * 64 + 256 * i) * 8;
            gload16(w1h + goff, &sm.p1.Bh[sbase]);
            gload16(w1l + goff, &sm.p1.Bl[sbase]);
        }
#pragma unroll
        for (int i = 0; i < 2; ++i) {
            int f4 = tid + 256 * i;
            int r = f4 >> 3;
            int kk = (f4 & 7) * 4;
            int gr = row0 + r;
            if (gr >= n) gr = n - 1;
            float4 v = *(const float4*)&x[(size_t)gr * IN_C + k0 + kk];
            float vv[4] = {v.x, v.y, v.z, v.w};
            bf16x4 h4, l4;
#pragma unroll
            for (int j = 0; j < 4; ++j) {
                __bf16 hb = (__bf16)vv[j];
                h4[j] = hb;
                l4[j] = (__bf16)(vv[j] - (float)hb);
            }
            *(bf16x4*)&sm.p1.Ah[r * 40 + kk] = h4;
            *(bf16x4*)&sm.p1.Al[r * 40 + kk] = l4;
        }
        __syncthreads();

        bf16x8 ah[4], al[4], bh[4], bl[4];
#pragma unroll
        for (int m = 0; m < 4; ++m) {
            int ao = (m * 16 + lr) * 40 + kg * 8;
            ah[m] = *(const bf16x8*)&sm.p1.Ah[ao];
            al[m] = *(const bf16x8*)&sm.p1.Al[ao];
        }
#pragma unroll
        for (int nf = 0; nf < 4; ++nf) {
            int row = w * 64 + nf * 16 + lr;
            int kc = kg ^ ((row >> 1) & 3);
            int bo = row * 32 + kc * 8;
            bh[nf] = *(const bf16x8*)&sm.p1.Bh[bo];
            bl[nf] = *(const bf16x8*)&sm.p1.Bl[bo];
        }
#pragma unroll
        for (int m = 0; m < 4; ++m)
#pragma unroll
            for (int nf = 0; nf < 4; ++nf) {
                acc[m][nf] = MFMA(ah[m], bh[nf], acc[m][nf]);
                acc[m][nf] = MFMA(ah[m], bl[nf], acc[m][nf]);
                acc[m][nf] = MFMA(al[m], bh[nf], acc[m][nf]);
            }
        __syncthreads();
    }

#pragma unroll
    for (int m = 0; m < 4; ++m)
#pragma unroll
        for (int nf = 0; nf < 4; ++nf) {
            int col = w * 64 + nf * 16 + lr;
            float bb = b1[col];
#pragma unroll
            for (int r = 0; r < 4; ++r) {
                int row = m * 16 + kg * 4 + r;
                float hv = acc[m][nf][r] + bb;
                hv = fmaxf(hv, 0.0f);
                __bf16 hb = (__bf16)hv;
                sm.p2.Hh[row * 264 + col] = hb;
                sm.p2.Hl[row * 264 + col] = (__bf16)(hv - (float)hb);
            }
        }
    __syncthreads();

    f32x4 acc2[4];
#pragma unroll
    for (int m = 0; m < 4; ++m) acc2[m] = (f32x4)0.0f;
    const int col2 = w * 16 + lr;

#pragma unroll
    for (int k0 = 0; k0 < HID_C; k0 += 32) {
        size_t wo = (size_t)col2 * HID_C + k0 + kg * 8;
        bf16x8 b2h = *(const bf16x8*)&w2h[wo];
        bf16x8 b2l = *(const bf16x8*)&w2l[wo];
#pragma unroll
        for (int m = 0; m < 4; ++m) {
            int ho = (m * 16 + lr) * 264 + k0 + kg * 8;
            bf16x8 a2h = *(const bf16x8*)&sm.p2.Hh[ho];
            bf16x8 a2l = *(const bf16x8*)&sm.p2.Hl[ho];
            acc2[m] = MFMA(a2h, b2h, acc2[m]);
            acc2[m] = MFMA(a2h, b2l, acc2[m]);
            acc2[m] = MFMA(a2l, b2h, acc2[m]);
        }
    }

    float bb2 = b2[col2];
#pragma unroll
    for (int m = 0; m < 4; ++m)
#pragma unroll
        for (int r = 0; r < 4; ++r) {
            int grow = row0 + m * 16 + kg * 4 + r;
            if (grow < n) {
                float vv = acc2[m][r] + bb2;
                h0[(size_t)grow * OUT_C + col2] = vv;
                hcur[(size_t)grow * OUT_C + col2] = vv;
            }
        }
}

// ---------------------------------------------------------------------------
// Propagation: hout[i] = 0.9*(sum_e w_e*hin[src_e] + dinv[i]^2*hin[i]) + 0.1*h0[i]
// One wave (64 lanes = 64 channels) per node, 4 nodes per block. Unroll x4 so
// four independent 256B gathers are in flight per wave.
// ---------------------------------------------------------------------------
__global__ __launch_bounds__(256) void k_prop(const float* __restrict__ hin,
                                              const float* __restrict__ h0,
                                              float* __restrict__ hout,
                                              const int* __restrict__ row_ptr,
                                              const int* __restrict__ csr_src,
                                              const float* __restrict__ csr_w,
                                              const float* __restrict__ dinv, int n) {
    int node = blockIdx.x * 4 + threadIdx.y;
    if (node >= n) return;
    int c = threadIdx.x;
    float dv = dinv[node];
    float acc = dv * dv * hin[(size_t)node * OUT_C + c];
    int e0 = row_ptr[node], e1 = row_ptr[node + 1];
    int e = e0;
    int e4 = e0 + ((e1 - e0) & ~3);
    for (; e < e4; e += 4) {
        int s0 = csr_src[e], s1 = csr_src[e + 1], s2 = csr_src[e + 2], s3 = csr_src[e + 3];
        float w0 = csr_w[e], w1v = csr_w[e + 1], w2v = csr_w[e + 2], w3v = csr_w[e + 3];
        float v0 = hin[(size_t)s0 * OUT_C + c];
        float v1 = hin[(size_t)s1 * OUT_C + c];
        float v2 = hin[(size_t)s2 * OUT_C + c];
        float v3 = hin[(size_t)s3 * OUT_C + c];
        acc += w0 * v0;
        acc += w1v * v1;
        acc += w2v * v2;
        acc += w3v * v3;
    }
    for (; e < e1; ++e) acc += csr_w[e] * hin[(size_t)csr_src[e] * OUT_C + c];
    hout[(size_t)node * OUT_C + c] = (1.0f - ALPHA) * acc + ALPHA * h0[(size_t)node * OUT_C + c];
}

// ---------------------------------------------------------------------------
extern "C" void kernel_launch(void* const* d_in, const int* in_sizes, int n_in,
                              void* d_out, int out_size, void* d_ws, size_t ws_size,
                              hipStream_t stream) {
    const float* x  = (const float*)d_in[0];
    const int*   ei = (const int*)d_in[1];
    const float* w1 = (const float*)d_in[2];
    const float* b1 = (const float*)d_in[3];
    const float* w2 = (const float*)d_in[4];
    const float* b2 = (const float*)d_in[5];
    float* dout = (float*)d_out;

    const int N = N_NODES;
    const int E = N_EDGES;
    const int G = (N + SCB - 1) / SCB;  // 98 scan blocks

    // workspace layout
    float* hB      = (float*)d_ws;                 // N*64
    float* h0      = hB + (size_t)N * OUT_C;       // N*64
    float* dinv    = h0 + (size_t)N * OUT_C;       // N
    int*   cnt     = (int*)(dinv + N);             // N
    int*   row_ptr = cnt + N;                      // N+1
    int*   cursor  = row_ptr + (N + 1);            // N
    int*   csr_src = cursor + N;                   // E
    float* csr_w   = (float*)(csr_src + E);        // E
    __bf16* w1h    = (__bf16*)(csr_w + E);         // 256*512
    __bf16* w1l    = w1h + (size_t)HID_C * IN_C;   // 256*512
    __bf16* w2h    = w1l + (size_t)HID_C * IN_C;   // 64*256
    __bf16* w2l    = w2h + (size_t)OUT_C * HID_C;  // 64*256
    int*   bsum    = (int*)(w2l + (size_t)OUT_C * HID_C);  // 128
    int*   boff    = bsum + 128;                           // 128

    hipMemsetAsync(cnt, 0, (size_t)N * sizeof(int), stream);

    k_count<<<(E + 255) / 256, 256, 0, stream>>>(ei, cnt, E);
    k_dinv<<<(N + 255) / 256, 256, 0, stream>>>(cnt, dinv, N);
    k_scan1<<<G, 256, 0, stream>>>(cnt, bsum, N);
    k_scan2<<<1, 128, 0, stream>>>(bsum, boff, G, row_ptr, N, E);
    k_scan3<<<G, 256, 0, stream>>>(cnt, boff, row_ptr, cursor, N);
    k_fill<<<(E + 255) / 256, 256, 0, stream>>>(ei, dinv, cursor, csr_src, csr_w, E);

    k_split<<<(HID_C * IN_C + 255) / 256, 256, 0, stream>>>(w1, w1h, w1l, HID_C * IN_C);
    k_split<<<(OUT_C * HID_C + 255) / 256, 256, 0, stream>>>(w2, w2h, w2l, OUT_C * HID_C);

    k_mlp2<<<(N + 63) / 64, 256, 0, stream>>>(x, w1h, w1l, b1, w2h, w2l, b2, h0, dout, N);

    for (int it = 0; it < K_ITERS; ++it) {
        const float* pin = (it & 1) ? hB : dout;
        float* pout = (it & 1) ? dout : hB;
        dim3 blk(64, 4);
        k_prop<<<(N + 3) / 4, blk, 0, stream>>>(pin, h0, pout, row_ptr, csr_src, csr_w, dinv, N);
    }
}

// Round 4
// 1016.946 us; speedup vs baseline: 2.4370x; 1.0896x over previous
//
#include <hip/hip_runtime.h>
#include <hip/hip_bf16.h>

#define N_NODES 100000
#define N_EDGES 1600000
#define IN_C 512
#define HID_C 256
#define OUT_C 64
#define K_ITERS 10
#define ALPHA 0.1f

typedef __bf16 bf16x8 __attribute__((ext_vector_type(8)));
typedef __bf16 bf16x4 __attribute__((ext_vector_type(4)));
typedef float f32x4 __attribute__((ext_vector_type(4)));
typedef _Float16 f16;

#define MFMA(a, b, c) __builtin_amdgcn_mfma_f32_16x16x32_bf16((a), (b), (c), 0, 0, 0)

__device__ __forceinline__ void gload16(const void* g, void* l) {
    __builtin_amdgcn_global_load_lds(
        (const __attribute__((address_space(1))) unsigned int*)g,
        (__attribute__((address_space(3))) unsigned int*)l, 16, 0, 0);
}

// ---------------------------------------------------------------------------
// CSR build kernels
// ---------------------------------------------------------------------------
__global__ void k_count(const int* __restrict__ ei, int* __restrict__ cnt, int E) {
    int e = blockIdx.x * blockDim.x + threadIdx.x;
    if (e < E) atomicAdd(&cnt[ei[E + e]], 1);
}

__global__ void k_dinv(const int* __restrict__ cnt, float* __restrict__ dinv, int n) {
    int i = blockIdx.x * blockDim.x + threadIdx.x;
    if (i < n) dinv[i] = rsqrtf((float)cnt[i] + 1.0f);  // +1 for self-loop
}

// ---------------------------------------------------------------------------
// Two-level scan: 1024 elems/block (256 thr x 4).
// ---------------------------------------------------------------------------
#define SCB 1024
__global__ __launch_bounds__(256) void k_scan1(const int* __restrict__ cnt,
                                               int* __restrict__ bsum, int n) {
    __shared__ int s[256];
    int b = blockIdx.x, t = threadIdx.x;
    int base = b * SCB + t * 4;
    int local = 0;
#pragma unroll
    for (int j = 0; j < 4; ++j) {
        int i = base + j;
        if (i < n) local += cnt[i];
    }
    s[t] = local;
    __syncthreads();
    for (int off = 1; off < 256; off <<= 1) {
        int u = (t >= off) ? s[t - off] : 0;
        __syncthreads();
        s[t] += u;
        __syncthreads();
    }
    if (t == 255) bsum[b] = s[255];
}

__global__ __launch_bounds__(128) void k_scan2(const int* __restrict__ bsum,
                                               int* __restrict__ boff, int G,
                                               int* __restrict__ row_ptr, int n, int total) {
    __shared__ int s[128];
    int t = threadIdx.x;
    int v = (t < G) ? bsum[t] : 0;
    s[t] = v;
    __syncthreads();
    for (int off = 1; off < 128; off <<= 1) {
        int u = (t >= off) ? s[t - off] : 0;
        __syncthreads();
        s[t] += u;
        __syncthreads();
    }
    if (t < G) boff[t] = s[t] - v;
    if (t == 0) row_ptr[n] = total;
}

__global__ __launch_bounds__(256) void k_scan3(const int* __restrict__ cnt,
                                               const int* __restrict__ boff,
                                               int* __restrict__ row_ptr,
                                               int* __restrict__ cursor, int n) {
    __shared__ int s[256];
    int b = blockIdx.x, t = threadIdx.x;
    int base = b * SCB + t * 4;
    int c4[4];
    int local = 0;
#pragma unroll
    for (int j = 0; j < 4; ++j) {
        int i = base + j;
        c4[j] = (i < n) ? cnt[i] : 0;
        local += c4[j];
    }
    s[t] = local;
    __syncthreads();
    for (int off = 1; off < 256; off <<= 1) {
        int u = (t >= off) ? s[t - off] : 0;
        __syncthreads();
        s[t] += u;
        __syncthreads();
    }
    int run = boff[b] + s[t] - local;
#pragma unroll
    for (int j = 0; j < 4; ++j) {
        int i = base + j;
        if (i < n) {
            row_ptr[i] = run;
            cursor[i] = run;
            run += c4[j];
        }
    }
}

__global__ void k_fill(const int* __restrict__ ei, const float* __restrict__ dinv,
                       int* __restrict__ cursor, int* __restrict__ csr_src,
                       float* __restrict__ csr_w, int E) {
    int e = blockIdx.x * blockDim.x + threadIdx.x;
    if (e < E) {
        int s = ei[e];
        int d = ei[E + e];
        int pos = atomicAdd(&cursor[d], 1);
        csr_src[pos] = s;
        csr_w[pos] = dinv[s] * dinv[d];
    }
}

// ---------------------------------------------------------------------------
// Weight split: f32 -> (hi bf16, lo bf16), hi+lo ~ f32 to ~2^-16 rel.
// ---------------------------------------------------------------------------
__global__ void k_split(const float* __restrict__ in, __bf16* __restrict__ hi,
                        __bf16* __restrict__ lo, int n) {
    int i = blockIdx.x * blockDim.x + threadIdx.x;
    if (i < n) {
        float f = in[i];
        __bf16 h = (__bf16)f;
        hi[i] = h;
        lo[i] = (__bf16)(f - (float)h);
    }
}

// ---------------------------------------------------------------------------
// Fused split-bf16 MFMA MLP (GEMM internals unchanged from round 1).
// Epilogue now writes fp16 h0 and fp16 h-current for the propagation phase.
// ---------------------------------------------------------------------------
__global__ __launch_bounds__(256, 2) void k_mlp2(
    const float* __restrict__ x,
    const __bf16* __restrict__ w1h, const __bf16* __restrict__ w1l,
    const float* __restrict__ b1,
    const __bf16* __restrict__ w2h, const __bf16* __restrict__ w2l,
    const float* __restrict__ b2,
    f16* __restrict__ h016, f16* __restrict__ hcur16, int n) {
    __shared__ __align__(16) union {
        struct {
            __bf16 Ah[64 * 40];
            __bf16 Al[64 * 40];
            __bf16 Bh[256 * 32];
            __bf16 Bl[256 * 32];
        } p1;
        struct {
            __bf16 Hh[64 * 264];
            __bf16 Hl[64 * 264];
        } p2;
    } sm;

    const int tid = threadIdx.x;
    const int l = tid & 63;
    const int w = tid >> 6;
    const int lr = l & 15;
    const int kg = l >> 4;
    const int row0 = blockIdx.x * 64;

    f32x4 acc[4][4];
#pragma unroll
    for (int m = 0; m < 4; ++m)
#pragma unroll
        for (int nf = 0; nf < 4; ++nf) acc[m][nf] = (f32x4)0.0f;

    for (int k0 = 0; k0 < IN_C; k0 += 32) {
#pragma unroll
        for (int i = 0; i < 4; ++i) {
            int slot = tid + 256 * i;
            int row = slot >> 2;
            int kc = (slot & 3) ^ ((row >> 1) & 3);
            size_t goff = (size_t)row * IN_C + k0 + kc * 8;
            int sbase = (w * 64 + 256 * i) * 8;
            gload16(w1h + goff, &sm.p1.Bh[sbase]);
            gload16(w1l + goff, &sm.p1.Bl[sbase]);
        }
#pragma unroll
        for (int i = 0; i < 2; ++i) {
            int f4 = tid + 256 * i;
            int r = f4 >> 3;
            int kk = (f4 & 7) * 4;
            int gr = row0 + r;
            if (gr >= n) gr = n - 1;
            float4 v = *(const float4*)&x[(size_t)gr * IN_C + k0 + kk];
            float vv[4] = {v.x, v.y, v.z, v.w};
            bf16x4 h4, l4;
#pragma unroll
            for (int j = 0; j < 4; ++j) {
                __bf16 hb = (__bf16)vv[j];
                h4[j] = hb;
                l4[j] = (__bf16)(vv[j] - (float)hb);
            }
            *(bf16x4*)&sm.p1.Ah[r * 40 + kk] = h4;
            *(bf16x4*)&sm.p1.Al[r * 40 + kk] = l4;
        }
        __syncthreads();

        bf16x8 ah[4], al[4], bh[4], bl[4];
#pragma unroll
        for (int m = 0; m < 4; ++m) {
            int ao = (m * 16 + lr) * 40 + kg * 8;
            ah[m] = *(const bf16x8*)&sm.p1.Ah[ao];
            al[m] = *(const bf16x8*)&sm.p1.Al[ao];
        }
#pragma unroll
        for (int nf = 0; nf < 4; ++nf) {
            int row = w * 64 + nf * 16 + lr;
            int kc = kg ^ ((row >> 1) & 3);
            int bo = row * 32 + kc * 8;
            bh[nf] = *(const bf16x8*)&sm.p1.Bh[bo];
            bl[nf] = *(const bf16x8*)&sm.p1.Bl[bo];
        }
#pragma unroll
        for (int m = 0; m < 4; ++m)
#pragma unroll
            for (int nf = 0; nf < 4; ++nf) {
                acc[m][nf] = MFMA(ah[m], bh[nf], acc[m][nf]);
                acc[m][nf] = MFMA(ah[m], bl[nf], acc[m][nf]);
                acc[m][nf] = MFMA(al[m], bh[nf], acc[m][nf]);
            }
        __syncthreads();
    }

#pragma unroll
    for (int m = 0; m < 4; ++m)
#pragma unroll
        for (int nf = 0; nf < 4; ++nf) {
            int col = w * 64 + nf * 16 + lr;
            float bb = b1[col];
#pragma unroll
            for (int r = 0; r < 4; ++r) {
                int row = m * 16 + kg * 4 + r;
                float hv = acc[m][nf][r] + bb;
                hv = fmaxf(hv, 0.0f);
                __bf16 hb = (__bf16)hv;
                sm.p2.Hh[row * 264 + col] = hb;
                sm.p2.Hl[row * 264 + col] = (__bf16)(hv - (float)hb);
            }
        }
    __syncthreads();

    f32x4 acc2[4];
#pragma unroll
    for (int m = 0; m < 4; ++m) acc2[m] = (f32x4)0.0f;
    const int col2 = w * 16 + lr;

#pragma unroll
    for (int k0 = 0; k0 < HID_C; k0 += 32) {
        size_t wo = (size_t)col2 * HID_C + k0 + kg * 8;
        bf16x8 b2h = *(const bf16x8*)&w2h[wo];
        bf16x8 b2l = *(const bf16x8*)&w2l[wo];
#pragma unroll
        for (int m = 0; m < 4; ++m) {
            int ho = (m * 16 + lr) * 264 + k0 + kg * 8;
            bf16x8 a2h = *(const bf16x8*)&sm.p2.Hh[ho];
            bf16x8 a2l = *(const bf16x8*)&sm.p2.Hl[ho];
            acc2[m] = MFMA(a2h, b2h, acc2[m]);
            acc2[m] = MFMA(a2h, b2l, acc2[m]);
            acc2[m] = MFMA(a2l, b2h, acc2[m]);
        }
    }

    float bb2 = b2[col2];
#pragma unroll
    for (int m = 0; m < 4; ++m)
#pragma unroll
        for (int r = 0; r < 4; ++r) {
            int grow = row0 + m * 16 + kg * 4 + r;
            if (grow < n) {
                float vv = acc2[m][r] + bb2;
                size_t idx = (size_t)grow * OUT_C + col2;
                h016[idx] = (f16)vv;
                hcur16[idx] = (f16)vv;
            }
        }
}

// ---------------------------------------------------------------------------
// fp16 propagation: res = 0.9*(sum_e w_e*hin[src_e] + dinv^2*hin[i]) + 0.1*h0[i]
// One wave (64 lanes = 64 channels) per node, 4 nodes per block, x4 unroll so
// four independent 128B gathers are in flight per wave. Accumulation in fp32;
// state carried fp16 (halves gather bytes; hin fits L2 better at 12.8MB).
// Final iteration writes the fp32 result of the last aggregation to dout.
// ---------------------------------------------------------------------------
__global__ __launch_bounds__(256) void k_prop16(const f16* __restrict__ hin,
                                                const f16* __restrict__ h016,
                                                f16* __restrict__ hout,
                                                float* __restrict__ dout,
                                                const int* __restrict__ row_ptr,
                                                const int* __restrict__ csr_src,
                                                const float* __restrict__ csr_w,
                                                const float* __restrict__ dinv,
                                                int n, int final_iter) {
    int node = blockIdx.x * 4 + threadIdx.y;
    if (node >= n) return;
    int c = threadIdx.x;
    float dv = dinv[node];
    float acc = dv * dv * (float)hin[(size_t)node * OUT_C + c];
    int e0 = row_ptr[node], e1 = row_ptr[node + 1];
    int e = e0;
    int e4 = e0 + ((e1 - e0) & ~3);
    for (; e < e4; e += 4) {
        int s0 = csr_src[e], s1 = csr_src[e + 1], s2 = csr_src[e + 2], s3 = csr_src[e + 3];
        float w0 = csr_w[e], w1v = csr_w[e + 1], w2v = csr_w[e + 2], w3v = csr_w[e + 3];
        float v0 = (float)hin[(size_t)s0 * OUT_C + c];
        float v1 = (float)hin[(size_t)s1 * OUT_C + c];
        float v2 = (float)hin[(size_t)s2 * OUT_C + c];
        float v3 = (float)hin[(size_t)s3 * OUT_C + c];
        acc += w0 * v0;
        acc += w1v * v1;
        acc += w2v * v2;
        acc += w3v * v3;
    }
    for (; e < e1; ++e) acc += csr_w[e] * (float)hin[(size_t)csr_src[e] * OUT_C + c];
    size_t idx = (size_t)node * OUT_C + c;
    float res = (1.0f - ALPHA) * acc + ALPHA * (float)h016[idx];
    hout[idx] = (f16)res;
    if (final_iter) dout[idx] = res;
}

// ---------------------------------------------------------------------------
extern "C" void kernel_launch(void* const* d_in, const int* in_sizes, int n_in,
                              void* d_out, int out_size, void* d_ws, size_t ws_size,
                              hipStream_t stream) {
    const float* x  = (const float*)d_in[0];
    const int*   ei = (const int*)d_in[1];
    const float* w1 = (const float*)d_in[2];
    const float* b1 = (const float*)d_in[3];
    const float* w2 = (const float*)d_in[4];
    const float* b2 = (const float*)d_in[5];
    float* dout = (float*)d_out;

    const int N = N_NODES;
    const int E = N_EDGES;
    const int G = (N + SCB - 1) / SCB;  // 98 scan blocks

    // workspace layout
    f16*   h16A    = (f16*)d_ws;                   // N*64
    f16*   h16B    = h16A + (size_t)N * OUT_C;     // N*64
    f16*   h016    = h16B + (size_t)N * OUT_C;     // N*64
    float* dinv    = (float*)(h016 + (size_t)N * OUT_C);  // N
    int*   cnt     = (int*)(dinv + N);             // N
    int*   row_ptr = cnt + N;                      // N+1
    int*   cursor  = row_ptr + (N + 1);            // N
    int*   csr_src = cursor + N;                   // E
    float* csr_w   = (float*)(csr_src + E);        // E
    __bf16* w1h    = (__bf16*)(csr_w + E);         // 256*512
    __bf16* w1l    = w1h + (size_t)HID_C * IN_C;   // 256*512
    __bf16* w2h    = w1l + (size_t)HID_C * IN_C;   // 64*256
    __bf16* w2l    = w2h + (size_t)OUT_C * HID_C;  // 64*256
    int*   bsum    = (int*)(w2l + (size_t)OUT_C * HID_C);  // 128
    int*   boff    = bsum + 128;                           // 128

    hipMemsetAsync(cnt, 0, (size_t)N * sizeof(int), stream);

    k_count<<<(E + 255) / 256, 256, 0, stream>>>(ei, cnt, E);
    k_dinv<<<(N + 255) / 256, 256, 0, stream>>>(cnt, dinv, N);
    k_scan1<<<G, 256, 0, stream>>>(cnt, bsum, N);
    k_scan2<<<1, 128, 0, stream>>>(bsum, boff, G, row_ptr, N, E);
    k_scan3<<<G, 256, 0, stream>>>(cnt, boff, row_ptr, cursor, N);
    k_fill<<<(E + 255) / 256, 256, 0, stream>>>(ei, dinv, cursor, csr_src, csr_w, E);

    k_split<<<(HID_C * IN_C + 255) / 256, 256, 0, stream>>>(w1, w1h, w1l, HID_C * IN_C);
    k_split<<<(OUT_C * HID_C + 255) / 256, 256, 0, stream>>>(w2, w2h, w2l, OUT_C * HID_C);

    k_mlp2<<<(N + 63) / 64, 256, 0, stream>>>(x, w1h, w1l, b1, w2h, w2l, b2, h016, h16A, N);

    for (int it = 0; it < K_ITERS; ++it) {
        const f16* pin = (it & 1) ? h16B : h16A;
        f16* pout = (it & 1) ? h16A : h16B;
        dim3 blk(64, 4);
        k_prop16<<<(N + 3) / 4, blk, 0, stream>>>(pin, h016, pout, dout, row_ptr,
                                                  csr_src, csr_w, dinv, N,
                                                  it == K_ITERS - 1 ? 1 : 0);
    }
}